// Round 7
// baseline (148.465 us; speedup 1.0000x reference)
//
#include <hip/hip_runtime.h>

// ---- types ----
typedef __bf16        bf16x8 __attribute__((ext_vector_type(8)));
typedef float         f32x4  __attribute__((ext_vector_type(4)));
typedef unsigned short u16x4 __attribute__((ext_vector_type(4)));
typedef unsigned short u16x8 __attribute__((ext_vector_type(8)));
typedef unsigned int  u32x4  __attribute__((ext_vector_type(4)));

#define MFMA16(a,b,c) __builtin_amdgcn_mfma_f32_16x16x32_bf16((a),(b),(c),0,0,0)

static __device__ __forceinline__ unsigned short f2bf(float f) {
  unsigned int u = __builtin_bit_cast(unsigned int, f);
  u += 0x7fffu + ((u >> 16) & 1u);          // RNE; inputs are finite
  return (unsigned short)(u >> 16);
}
static __device__ __forceinline__ unsigned int pk2rne(float a, float b) {
  return (unsigned int)f2bf(a) | ((unsigned int)f2bf(b) << 16);
}
// packed f32x2 -> bf16x2: 1 inst on gfx950, guarded fallback otherwise
static __device__ __forceinline__ unsigned int pkrn(float a, float b) {
#if __has_builtin(__builtin_amdgcn_cvt_pk_bf16_f32)
  auto r = __builtin_amdgcn_cvt_pk_bf16_f32(a, b);   // src0 -> low half
  return __builtin_bit_cast(unsigned int, r);
#else
  return pk2rne(a, b);
#endif
}
static __device__ __forceinline__ bf16x8 as_bf(u32x4 v) {
  return __builtin_bit_cast(bf16x8, v);
}
static __device__ __forceinline__ float bf2f(unsigned short u) {
  return __builtin_bit_cast(float, ((unsigned int)u) << 16);
}

// Problem constants
#define SDIM 4096
#define CDIM 256
#define NHEAD 4
#define HDIM 64
#define NBATCH 2
#define KSPLIT 4

// ---------------------------------------------------------------------------
// 1) merged prep: blocks 0..255 = GN partial stats; 256..319 = weight cast to
//    FRAG-LINEAR bf16:  Wf[(ot*8+kc)*64 + lane]*8  holds W[ot*16+(l&15)][kc*32+(l>>4)*8 ..+8)
__global__ __launch_bounds__(256) void k_prep(const float* __restrict__ x,
                                              const float* __restrict__ wq,
                                              const float* __restrict__ wo,
                                              unsigned short* __restrict__ wqf,
                                              unsigned short* __restrict__ wof,
                                              float2* __restrict__ Sp) {
  int j = blockIdx.x, i = threadIdx.x;
  if (j < 256) {
    const float* p = x + (size_t)(j >> 3) * 65536 + (size_t)(j & 7) * 8192;
    float s = 0.f, sq = 0.f;
#pragma unroll
    for (int r = 0; r < 8; ++r) {
      float4 v = *(const float4*)(p + (r * 256 + i) * 4);
      s  += v.x + v.y + v.z + v.w;
      sq += v.x * v.x + v.y * v.y + v.z * v.z + v.w * v.w;
    }
    __shared__ float rs[256], rq[256];
    rs[i] = s; rq[i] = sq;
    __syncthreads();
    for (int off = 128; off > 0; off >>= 1) {
      if (i < off) { rs[i] += rs[i + off]; rq[i] += rq[i + off]; }
      __syncthreads();
    }
    if (i == 0) Sp[j] = make_float2(rs[0], rq[0]);
  } else {
    int t = (j - 256) * 256 + i;          // 0..16383, 2 frag-rows each
#pragma unroll
    for (int u = 0; u < 2; ++u) {
      int G = t * 2 + u;                  // 0..32767 = 24576 (wq) + 8192 (wo)
      const float* src; unsigned short* dst;
      if (G < 24576) {
        int tile = G >> 6, l = G & 63;
        src = wq + (size_t)((tile >> 3) * 16 + (l & 15)) * 256 + (tile & 7) * 32 + (l >> 4) * 8;
        dst = wqf + (size_t)G * 8;
      } else {
        int G2 = G - 24576, tile = G2 >> 6, l = G2 & 63;
        src = wo + (size_t)((tile >> 3) * 16 + (l & 15)) * 256 + (tile & 7) * 32 + (l >> 4) * 8;
        dst = wof + (size_t)G2 * 8;
      }
      float4 v0 = *(const float4*)src, v1 = *(const float4*)(src + 4);
      u16x8 r;
      r[0] = f2bf(v0.x); r[1] = f2bf(v0.y); r[2] = f2bf(v0.z); r[3] = f2bf(v0.w);
      r[4] = f2bf(v1.x); r[5] = f2bf(v1.y); r[6] = f2bf(v1.z); r[7] = f2bf(v1.w);
      *(u16x8*)dst = r;
    }
  }
}

// ---------------------------------------------------------------------------
// 2) GN apply + transpose: x[b][c][s] fp32 -> Xf frag-linear bf16:
//    Xf[((b*256 + st)*8 + kc)*64 + lane]*8 = X[st*16+(l&15)][kc*32+(l>>4)*8..+8)
__global__ __launch_bounds__(256) void k_gn_apply(const float* __restrict__ x,
                                                  const float2* __restrict__ Sp,
                                                  const float* __restrict__ gnw,
                                                  const float* __restrict__ gnb,
                                                  unsigned short* __restrict__ Xf) {
  __shared__ __attribute__((aligned(16))) unsigned short sT[64 * 268];
  __shared__ float2 sStat[16];
  int b = blockIdx.y, s0 = blockIdx.x * 64;
  int i = threadIdx.x, lane = i & 63, w = i >> 6;
  if (i < 16) {
    float s = 0.f, sq = 0.f;
#pragma unroll
    for (int u = 0; u < 8; ++u) {
      float2 v = Sp[(b * 16 + i) * 8 + u];
      s += v.x; sq += v.y;
    }
    float mean = s * (1.f / 65536.f);
    float var  = sq * (1.f / 65536.f) - mean * mean;
    sStat[i] = make_float2(mean, rsqrtf(var + 1e-5f));
  }
  __syncthreads();
#pragma unroll 4
  for (int r = 0; r < 64; ++r) {
    int c = r * 4 + w;
    float v = x[((size_t)(b * CDIM + c)) * SDIM + s0 + lane];
    float2 st = sStat[c >> 4];
    float nv = (v - st.x) * st.y * gnw[c] + gnb[c];
    sT[lane * 268 + c] = f2bf(nv);
  }
  __syncthreads();
  int l = i & 63, fr = i >> 6;
#pragma unroll
  for (int g = 0; g < 8; ++g) {
    int tile = fr * 8 + g, st = tile >> 3, kc = tile & 7;
    const unsigned short* src = &sT[(st * 16 + (l & 15)) * 268 + kc * 32 + (l >> 4) * 8];
    u16x4 lo = *(const u16x4*)src, hi = *(const u16x4*)(src + 4);
    unsigned short* dst = Xf + (((size_t)(b * 256 + (s0 >> 4) + st) * 8 + kc) * 64 + l) * 8;
    *(u16x4*)dst = lo;
    *(u16x4*)(dst + 4) = hi;
  }
}

// ---------------------------------------------------------------------------
// 3/5) Barrier-free GEMM: D[o][s] = sum_c W[o][c] X[s][c], K=256, all operands
//    frag-linear in global (L1/L2-resident). Per wave: 16o x 64s, 8 kc steps.
//  MODE 0 (QKV): epilogue repacks into attention frag-linear layouts:
//    Qf/Kf[bh][t16=s/16][ks=d/32][lane][8]  (Q pre-scaled by log2(e)/16)
//    Vf[bh][t32=s/32][dt=d/16][lane][8]
//  MODE 1 (proj): fp32 + bias + residual -> outf[b][o][s]
template <int M, int MODE>
__global__ __launch_bounds__(256) void k_gemm(const unsigned short* __restrict__ Wf,
                                              const unsigned short* __restrict__ Xf,
                                              unsigned short* __restrict__ Qf,
                                              unsigned short* __restrict__ Kf,
                                              unsigned short* __restrict__ Vf,
                                              float* __restrict__ outf,
                                              const float* __restrict__ bias,
                                              const float* __restrict__ resid) {
  __shared__ __attribute__((aligned(16))) unsigned short sB[64 * 68];  // epilogue bounce
  int b = blockIdx.z, s0 = blockIdx.y * 64, o0 = blockIdx.x * 64;
  int i = threadIdx.x, lane = i & 63, w = i >> 6;
  int quad = lane >> 4, m = lane & 15;
  int ot = blockIdx.x * 4 + w;        // global 16-o tile
  int stg = s0 >> 4;                  // global 16-s tile base

  f32x4 acc[4] = {};
#pragma unroll
  for (int kc = 0; kc < 8; ++kc) {
    bf16x8 aW = as_bf(*(const u32x4*)(Wf + (((size_t)ot * 8 + kc) * 64 + lane) * 8));
#pragma unroll
    for (int st = 0; st < 4; ++st) {
      bf16x8 bX = as_bf(*(const u32x4*)(Xf + ((((size_t)b * 256 + stg + st) * 8 + kc) * 64 + lane) * 8));
      acc[st] = MFMA16(aW, bX, acc[st]);
    }
  }

  if (MODE == 1) {
#pragma unroll
    for (int st = 0; st < 4; ++st)
#pragma unroll
      for (int r = 0; r < 4; ++r) {
        int o = o0 + w * 16 + quad * 4 + r;
        int s = s0 + st * 16 + m;
        size_t idx = ((size_t)b * M + o) * SDIM + s;
        outf[idx] = acc[st][r] + bias[o] + resid[idx];
      }
  } else {
    int sec = (o0 >> 6) % 3;             // 0=Q, 1=K, 2=V
    int h   = o0 / 192;
    int bh  = b * NHEAD + h;
    float qs = (sec == 0) ? 0.09016844f : 1.0f;   // log2(e)/16 folded into Q
#pragma unroll
    for (int st = 0; st < 4; ++st) {
      uint2 pk = make_uint2(pk2rne(acc[st][0] * qs, acc[st][1] * qs),
                            pk2rne(acc[st][2] * qs, acc[st][3] * qs));
      *(uint2*)&sB[(st * 16 + m) * 68 + w * 16 + quad * 4] = pk;
    }
    __syncthreads();
    int lp = i & 63, qp = lp >> 4, mp = lp & 15, t = i >> 6;
    if (sec < 2) {
      unsigned short* base = (sec == 0) ? Qf : Kf;
#pragma unroll
      for (int ks = 0; ks < 2; ++ks) {
        const unsigned short* src = &sB[(t * 16 + mp) * 68 + ks * 32 + qp * 8];
        u16x4 lo = *(const u16x4*)src;
        u16x4 hi = *(const u16x4*)(src + 4);
        unsigned short* dst = base + ((((size_t)bh * 256 + (s0 >> 4) + t) * 2 + ks) * 64 + lp) * 8;
        *(u16x4*)dst = lo;
        *(u16x4*)(dst + 4) = hi;
      }
    } else {
      int kt32l = t >> 1, dts = (t & 1) * 2;
#pragma unroll
      for (int dd = 0; dd < 2; ++dd) {
        int dt = dts + dd;
        u16x8 v;
#pragma unroll
        for (int jj = 0; jj < 8; ++jj)
          v[jj] = sB[(kt32l * 32 + qp * 8 + jj) * 68 + dt * 16 + mp];
        unsigned short* dst = Vf + ((((size_t)bh * 128 + (s0 >> 5) + kt32l) * 4 + dt) * 64 + lp) * 8;
        *(u16x8*)dst = v;
      }
    }
  }
}

// ---------------------------------------------------------------------------
// 4) Flash attention v4: BARRIER-FREE. 32q/wave, K/V frags loaded directly
//    from global (frag-linear, coalesced; 4-wave redundancy absorbed by L1).
//    li accumulated by an extra MFMA with all-ones A (contracts all 32 keys
//    -> no epilogue shuffles). sP is wave-private (lgkm only, no barrier).
//    Partials: Opb bf16 [ks][bh][q][64], Lp fp32 [ks][bh][q].
__global__ __launch_bounds__(256, 4) void k_attn(const unsigned short* __restrict__ Qf,
                                                 const unsigned short* __restrict__ Kf,
                                                 const unsigned short* __restrict__ Vf,
                                                 unsigned short* __restrict__ Opb,
                                                 float* __restrict__ Lp) {
  __shared__ __attribute__((aligned(16))) unsigned short sP[4][32 * 40];
  int bh = blockIdx.y, kk = blockIdx.z;
  int i = threadIdx.x, lane = i & 63, w = i >> 6;
  int quad = lane >> 4, m = lane & 15;
  constexpr int ITERS = SDIM / KSPLIT / 32;

  // Q B-frags: wave w owns q-tiles {blockIdx.x*8 + w*2, +1}
  bf16x8 bq[2][2];
#pragma unroll
  for (int qt = 0; qt < 2; ++qt)
#pragma unroll
    for (int ks = 0; ks < 2; ++ks)
      bq[qt][ks] = as_bf(*(const u32x4*)(Qf +
        ((((size_t)bh * 256 + (blockIdx.x * 8 + w * 2 + qt)) * 2 + ks) * 64 + lane) * 8));

  bf16x8 aone;   // all-ones A fragment for the li MFMA
  {
    u16x8 t;
#pragma unroll
    for (int jj = 0; jj < 8; ++jj) t[jj] = 0x3F80;   // 1.0 bf16
    aone = __builtin_bit_cast(bf16x8, t);
  }

  f32x4 oacc[2][4] = {};
  f32x4 liacc[2] = {};

  for (int it = 0; it < ITERS; ++it) {
    // K/V frags direct from global (coalesced 1KB/instr; L1-hot across waves)
    bf16x8 ak[2][2], av[4];
    int kb16 = kk * (ITERS * 2) + it * 2;
#pragma unroll
    for (int ky = 0; ky < 2; ++ky)
#pragma unroll
      for (int ks = 0; ks < 2; ++ks)
        ak[ky][ks] = as_bf(*(const u32x4*)(Kf +
          ((((size_t)bh * 256 + kb16 + ky) * 2 + ks) * 64 + lane) * 8));
    int kb32 = kk * ITERS + it;
#pragma unroll
    for (int dt = 0; dt < 4; ++dt)
      av[dt] = as_bf(*(const u32x4*)(Vf +
        ((((size_t)bh * 128 + kb32) * 4 + dt) * 64 + lane) * 8));

    // QK^T + softmax + pack
#pragma unroll
    for (int qt = 0; qt < 2; ++qt) {
      f32x4 sc0 = {-18.f, -18.f, -18.f, -18.f};   // fixed-max shift in C-init
      f32x4 sc1 = sc0;
      sc0 = MFMA16(ak[0][0], bq[qt][0], sc0);
      sc0 = MFMA16(ak[0][1], bq[qt][1], sc0);
      sc1 = MFMA16(ak[1][0], bq[qt][0], sc1);
      sc1 = MFMA16(ak[1][1], bq[qt][1], sc1);
      float p[8];
#pragma unroll
      for (int r = 0; r < 4; ++r) {
        p[r]     = __builtin_amdgcn_exp2f(sc0[r]);
        p[4 + r] = __builtin_amdgcn_exp2f(sc1[r]);
      }
      int row = (qt * 16 + m) * 40;
      *(uint2*)&sP[w][row + quad * 4]      = make_uint2(pkrn(p[0], p[1]), pkrn(p[2], p[3]));
      *(uint2*)&sP[w][row + 16 + quad * 4] = make_uint2(pkrn(p[4], p[5]), pkrn(p[6], p[7]));
    }
    // PV + li (sP same-wave: compiler inserts lgkm wait, no barrier)
#pragma unroll
    for (int qt = 0; qt < 2; ++qt) {
      bf16x8 bp = *(const bf16x8*)&sP[w][(qt * 16 + m) * 40 + quad * 8];
#pragma unroll
      for (int dt = 0; dt < 4; ++dt)
        oacc[qt][dt] = MFMA16(av[dt], bp, oacc[qt][dt]);
      liacc[qt] = MFMA16(aone, bp, liacc[qt]);
    }
  }

  // epilogue: liacc rows are all equal (ones-A) and include all 32 keys
  size_t qg = (size_t)(kk * 8 + bh) * SDIM + blockIdx.x * 128 + w * 32;
  if (quad == 0) {
#pragma unroll
    for (int qt = 0; qt < 2; ++qt) Lp[qg + qt * 16 + m] = liacc[qt][0];
  }
#pragma unroll
  for (int qt = 0; qt < 2; ++qt)
#pragma unroll
    for (int dt = 0; dt < 4; ++dt) {
      uint2 pk = make_uint2(pk2rne(oacc[qt][dt][0], oacc[qt][dt][1]),
                            pk2rne(oacc[qt][dt][2], oacc[qt][dt][3]));
      *(uint2*)&Opb[(qg + qt * 16 + m) * 64 + dt * 16 + quad * 4] = pk;
    }
}

// ---------------------------------------------------------------------------
// 5) combine partials -> aof FRAG-LINEAR (proj GEMM's X layout):
//    aof[((b*256+st)*8+kc)*64 + lane]*8
__global__ __launch_bounds__(256) void k_combine(const unsigned short* __restrict__ Opb,
                                                 const float* __restrict__ Lp,
                                                 unsigned short* __restrict__ aof) {
  int gid = blockIdx.x * 256 + threadIdx.x;
  int bh = gid >> 14, rem = gid & 16383, q = rem >> 2, dq = rem & 3;
  float li = 0.f, o[16];
#pragma unroll
  for (int e = 0; e < 16; ++e) o[e] = 0.f;
#pragma unroll
  for (int ks = 0; ks < KSPLIT; ++ks) {
    size_t base = (size_t)(ks * 8 + bh) * SDIM + q;
    li += Lp[base];
    const unsigned short* p = Opb + base * 64 + dq * 16;
    u16x8 a = *(const u16x8*)p, b2 = *(const u16x8*)(p + 8);
#pragma unroll
    for (int e = 0; e < 8; ++e) { o[e] += bf2f(a[e]); o[8 + e] += bf2f(b2[e]); }
  }
  float inv = 1.f / li;
  unsigned int dw[8];
#pragma unroll
  for (int e = 0; e < 8; ++e) dw[e] = pk2rne(o[2 * e] * inv, o[2 * e + 1] * inv);
  int b = bh >> 2, c0 = (bh & 3) * 64 + dq * 16;
  int st = q >> 4, mm = q & 15, kc = c0 >> 5, qd = (c0 >> 3) & 3;
  unsigned short* base = aof + (((size_t)(b * 256 + st) * 8 + kc) * 64) * 8;
  *(u32x4*)(base + (qd * 16 + mm) * 8)       = u32x4{dw[0], dw[1], dw[2], dw[3]};
  *(u32x4*)(base + ((qd + 1) * 16 + mm) * 8) = u32x4{dw[4], dw[5], dw[6], dw[7]};
}

// ---------------------------------------------------------------------------
extern "C" void kernel_launch(void* const* d_in, const int* in_sizes, int n_in,
                              void* d_out, int out_size, void* d_ws, size_t ws_size,
                              hipStream_t stream) {
  const float* input = (const float*)d_in[0];
  const float* gnw   = (const float*)d_in[1];
  const float* gnb   = (const float*)d_in[2];
  const float* wq    = (const float*)d_in[3];
  const float* wo    = (const float*)d_in[4];
  const float* ob    = (const float*)d_in[5];
  float* out = (float*)d_out;

  char* ws = (char*)d_ws;
  unsigned short* Xf  = (unsigned short*)(ws);                        // 4 MB frag-linear GN(x)
  unsigned short* Qf  = (unsigned short*)(ws + (4ull  << 20));        // 4 MB
  unsigned short* Kf  = (unsigned short*)(ws + (8ull  << 20));        // 4 MB
  unsigned short* Vf  = (unsigned short*)(ws + (12ull << 20));        // 4 MB
  unsigned short* aof = (unsigned short*)(ws + (16ull << 20));        // 4 MB frag-linear attn-out
  unsigned short* wqf = (unsigned short*)(ws + (20ull << 20));        // 384 KB frag-linear
  unsigned short* wof = (unsigned short*)(ws + (20ull << 20) + (1u << 19)); // 128 KB
  float2* Sp          = (float2*)(ws + (20ull << 20) + (3u << 18));   // 2 KB
  float* Lp           = (float*)(ws + (21ull << 20));                 // 512 KB
  unsigned short* Opb = (unsigned short*)(ws + (22ull << 20));        // 16 MB

  k_prep<<<320, 256, 0, stream>>>(input, wq, wo, wqf, wof, Sp);
  k_gn_apply<<<dim3(64, NBATCH), 256, 0, stream>>>(input, Sp, gnw, gnb, Xf);
  k_gemm<768, 0><<<dim3(12, 64, NBATCH), 256, 0, stream>>>(wqf, Xf, Qf, Kf, Vf, nullptr, nullptr, nullptr);
  k_attn<<<dim3(32, NHEAD * NBATCH, KSPLIT), 256, 0, stream>>>(Qf, Kf, Vf, Opb, Lp);
  k_combine<<<512, 256, 0, stream>>>(Opb, Lp, aof);
  k_gemm<256, 1><<<dim3(4, 64, NBATCH), 256, 0, stream>>>(wof, aof, nullptr, nullptr, nullptr, out, ob, input);
}